// Round 11
// baseline (1730.129 us; speedup 1.0000x reference)
//
#include <hip/hip_runtime.h>
#include <hip/hip_bf16.h>
#include <stdint.h>

typedef __attribute__((ext_vector_type(8))) short short8;
typedef __attribute__((ext_vector_type(4))) float f32x4;

#define B_ 32
#define N_ 196
#define D_ 1024
#define V_ 32000
#define NSTEP 99
#define MROWS 3168   // 99*32
#define MPAD  3200
#define SENT  0x7FC07FC07FC07FC0ULL   // 4x bf16 NaN: unreachable as packed h (|h|<1)

// workspace layout (bytes)
#define OFF_WT    0ULL          // bf16 [32000][1024]  = 65,536,000
#define OFF_H     65536000ULL   // bf16 [3200][1024]   =  6,553,600  (u64 view: [99][8192] + pad rows)
#define OFF_FSUM  72089600ULL   // f32  [32][1024]
#define OFF_CTX   72220672ULL   // f32  [32][1024]
#define OFF_GBASE 72351744ULL   // f32  [32][4096]

#define AS3 __attribute__((address_space(3)))
#define AS1 __attribute__((address_space(1)))
static __device__ __forceinline__ void gload_lds16(const void* g, void* l) {
  __builtin_amdgcn_global_load_lds((const AS1 uint32_t*)g, (AS3 uint32_t*)l, 16, 0, 0);
}

// ---------------- sentinel-fill H[0..99) steps (u64 view) ----------------
__global__ void k_init(unsigned long long* __restrict__ Hq) {
  int base = (blockIdx.x * 256 + threadIdx.x) * 4;   // grid 792 -> 811,008 words
  #pragma unroll
  for (int j = 0; j < 4; ++j) Hq[base + j] = SENT;
}

// ---------------- fsum[b,e] = sum_n relu(features[b,n,e]) ----------------
__global__ void k_fsum(const float* __restrict__ feat, float* __restrict__ fsum) {
  int idx = blockIdx.x * 256 + threadIdx.x;           // 32768
  int b = idx >> 10, e = idx & 1023;
  const float* p = feat + (size_t)b * (N_ * D_) + e;
  float s = 0.f;
  #pragma unroll 4
  for (int n = 0; n < N_; ++n) s += fmaxf(p[(size_t)n * D_], 0.f);
  fsum[idx] = s;
}

// ---------------- ctx = fsum @ W_fv + 196*b_fv  (16-batch LDS, W_fv read 2x) ----------------
__global__ void k_ctx(const float* __restrict__ fsum, const float* __restrict__ W_fv,
                      const float* __restrict__ b_fv, float* __restrict__ ctx) {
  __shared__ float fs[16][1024];                      // 64 KB
  int b0 = blockIdx.y * 16;                           // grid (16,2)
  int d = blockIdx.x * 64 + (threadIdx.x & 63);
  int bq = threadIdx.x >> 6;                          // 4 batch-quads
  for (int i = threadIdx.x; i < 16384; i += 256)
    fs[i >> 10][i & 1023] = fsum[(b0 + (i >> 10)) * 1024 + (i & 1023)];
  __syncthreads();
  float bias = 196.f * b_fv[d];
  float acc[4] = {bias, bias, bias, bias};
  for (int e4 = 0; e4 < 256; ++e4) {
    float w0 = W_fv[(size_t)(4 * e4 + 0) * 1024 + d];
    float w1 = W_fv[(size_t)(4 * e4 + 1) * 1024 + d];
    float w2 = W_fv[(size_t)(4 * e4 + 2) * 1024 + d];
    float w3 = W_fv[(size_t)(4 * e4 + 3) * 1024 + d];
    #pragma unroll
    for (int r = 0; r < 4; ++r) {
      float4 c = *(const float4*)&fs[bq * 4 + r][e4 * 4];
      acc[r] = fmaf(c.x, w0, fmaf(c.y, w1, fmaf(c.z, w2, fmaf(c.w, w3, acc[r]))));
    }
  }
  #pragma unroll
  for (int r = 0; r < 4; ++r) ctx[(size_t)(b0 + bq * 4 + r) * 1024 + d] = acc[r];
}

// ---------------- gbase = ctx @ W_ih + b_ih + b_hh  (16-batch LDS, W_ih read 2x) ----------------
__global__ void k_gbase(const float* __restrict__ ctx, const float* __restrict__ W_ih,
                        const float* __restrict__ b_ih, const float* __restrict__ b_hh,
                        float* __restrict__ gbase) {
  __shared__ float cs[16][1024];                      // 64 KB
  int b0 = blockIdx.y * 16;                           // grid (16,2)
  int j = blockIdx.x * 256 + threadIdx.x;
  for (int i = threadIdx.x; i < 16384; i += 256)
    cs[i >> 10][i & 1023] = ctx[(size_t)(b0 + (i >> 10)) * 1024 + (i & 1023)];
  __syncthreads();
  float bias = b_ih[j] + b_hh[j];
  float acc[16];
  #pragma unroll
  for (int r = 0; r < 16; ++r) acc[r] = bias;
  for (int e4 = 0; e4 < 256; ++e4) {
    float w0 = W_ih[(size_t)(4 * e4 + 0) * 4096 + j];
    float w1 = W_ih[(size_t)(4 * e4 + 1) * 4096 + j];
    float w2 = W_ih[(size_t)(4 * e4 + 2) * 4096 + j];
    float w3 = W_ih[(size_t)(4 * e4 + 3) * 4096 + j];
    #pragma unroll
    for (int r = 0; r < 16; ++r) {
      float4 c = *(const float4*)&cs[r][e4 * 4];
      acc[r] = fmaf(c.x, w0, fmaf(c.y, w1, fmaf(c.z, w2, fmaf(c.w, w3, acc[r]))));
    }
  }
  #pragma unroll
  for (int r = 0; r < 16; ++r) gbase[(size_t)(b0 + r) * 4096 + j] = acc[r];
}

// ---------------- persistent LSTM recurrence (blocks 0..127) + workers (128..255) ----------------
// Sentinel-payload exchange into H[t] (packed 4xbf16 u64 agent atomics, written once).
// Consumers poll with a per-thread NEED bitmask (re-polls touch only missing words).
__global__ __launch_bounds__(256, 1) void k_rec(
    const float* __restrict__ gbase, const float* __restrict__ W_hh,
    const float* __restrict__ bos, unsigned long long* __restrict__ Hq,
    const float* __restrict__ W_lm, __hip_bfloat16* __restrict__ WT,
    float* __restrict__ out) {
  extern __shared__ char lds[];
  const int tid = threadIdx.x;
  const int blk = blockIdx.x;

  if (blk >= 128) {
    // ---------- worker blocks ----------
    __hip_bfloat16* t = (__hip_bfloat16*)lds;          // [64][66]
    int wblk = blk - 128;
    for (int idx = wblk * 256 + tid; idx < B_ * V_; idx += 128 * 256)
      out[idx] = ((idx % V_) == 0) ? 1.0f : 0.0f;
    // zero the TRUE pad rows 3168..3199: u64 word offset MROWS*256 (256 u64 per row)
    if (wblk < 64) ((uint32_t*)(Hq + (size_t)MROWS * 256))[wblk * 256 + tid] = 0u;
    int tx = tid & 63, ty = tid >> 6;
    int word = tx & 31, nh = tx >> 5;
    for (int tile = wblk; tile < 8000; tile += 128) {
      int k0 = (tile & 15) * 64;
      int n0 = (tile >> 4) * 64;
      __syncthreads();
      #pragma unroll
      for (int i = 0; i < 16; ++i) {
        int r = i * 4 + ty;
        t[r * 66 + tx] = __float2bfloat16(W_lm[(size_t)(k0 + r) * V_ + n0 + tx]);
      }
      __syncthreads();
      #pragma unroll
      for (int i = 0; i < 8; ++i) {
        int n = i * 8 + ty * 2 + nh;
        uint32_t lo = *(const uint16_t*)&t[2 * word * 66 + n];
        uint32_t hi = *(const uint16_t*)&t[(2 * word + 1) * 66 + n];
        ((uint32_t*)&WT[(size_t)(n0 + n) * 1024 + k0])[word] = lo | (hi << 16);
      }
    }
    return;
  }

  // ---------- recurrence blocks ----------
  __hip_bfloat16* hbuf = (__hip_bfloat16*)lds;             // [32][1024] bf16 swizzled (64KB)
  __hip_bfloat16* wbuf = (__hip_bfloat16*)(lds + 65536);   // [32cols][1024] (init only)
  float* gex = (float*)(lds + 131072);                     // [32][33] f32

  const int d0 = blk * 8;

  for (int idx = tid; idx < 32 * 1024; idx += 256) {
    int c = idx & 31;
    int k = idx >> 5;
    int gcol = ((c >> 3) << 10) + d0 + (c & 7);
    float w = W_hh[(size_t)k * 4096 + gcol];
    wbuf[c * 1024 + ((((k >> 3) ^ (c & 7)) << 3) | (k & 7))] = __float2bfloat16(w);
  }
  for (int idx = tid; idx < 32 * 1024; idx += 256) {
    int row = idx >> 10;
    int k = idx & 1023;
    hbuf[row * 1024 + ((((k >> 3) ^ (row & 7)) << 3) | (k & 7))] = __float2bfloat16(bos[k]);
  }

  const int tb = tid >> 3;     // batch 0..31
  const int tdl = tid & 7;     // local dim 0..7
  float gb0 = gbase[(size_t)tb * 4096 + 0 * 1024 + d0 + tdl];
  float gb1 = gbase[(size_t)tb * 4096 + 1 * 1024 + d0 + tdl];
  float gb2 = gbase[(size_t)tb * 4096 + 2 * 1024 + d0 + tdl];
  float gb3 = gbase[(size_t)tb * 4096 + 3 * 1024 + d0 + tdl];
  float cst = 0.f;

  const int lane = tid & 63;
  const int wid = tid >> 6;
  const int wm = wid & 1;
  const int wn = wid >> 1;
  const int arow = wm * 16 + (lane & 15);
  const int bcol = wn * 16 + (lane & 15);
  const int kg = lane >> 4;
  const int axor = arow & 7;

  __syncthreads();

  short8 breg[32];
  #pragma unroll
  for (int kt = 0; kt < 32; ++kt) {
    int ca = kt * 4 + kg;
    breg[kt] = *(const short8*)&wbuf[bcol * 1024 + ((ca ^ (bcol & 7)) << 3)];
  }

  const int pubw = tb * 256 + blk * 2 + (tdl >> 2);

  for (int t = 0; t < NSTEP; ++t) {
    f32x4 acc0 = {0.f, 0.f, 0.f, 0.f};
    f32x4 acc1 = {0.f, 0.f, 0.f, 0.f};
    #pragma unroll
    for (int kt = 0; kt < 32; kt += 2) {
      int ca = kt * 4 + kg;
      short8 a0 = *(const short8*)&hbuf[arow * 1024 + ((ca ^ axor) << 3)];
      acc0 = __builtin_amdgcn_mfma_f32_16x16x32_bf16(a0, breg[kt], acc0, 0, 0, 0);
      short8 a1 = *(const short8*)&hbuf[arow * 1024 + (((ca + 4) ^ axor) << 3)];
      acc1 = __builtin_amdgcn_mfma_f32_16x16x32_bf16(a1, breg[kt + 1], acc1, 0, 0, 0);
    }
    acc0 = acc0 + acc1;
    {
      int bq = wm * 16 + ((lane >> 4) << 2);
      #pragma unroll
      for (int q = 0; q < 4; ++q) gex[(bq + q) * 33 + bcol] = acc0[q];
    }
    __syncthreads();   // S1

    float gi = gex[tb * 33 + 0  + tdl] + gb0;
    float gf = gex[tb * 33 + 8  + tdl] + gb1;
    float gg = gex[tb * 33 + 16 + tdl] + gb2;
    float go = gex[tb * 33 + 24 + tdl] + gb3;
    float si = 1.f / (1.f + __expf(-gi));
    float sf = 1.f / (1.f + __expf(-gf));
    float so = 1.f / (1.f + __expf(-go));
    cst = sf * cst + si * tanhf(gg);
    float h = so * tanhf(cst);

    // publish packed 4x bf16 straight into H[t]
    float h1 = __shfl_down(h, 1);
    float h2 = __shfl_down(h, 2);
    float h3 = __shfl_down(h, 3);
    if ((tdl & 3) == 0) {
      __hip_bfloat16 q0 = __float2bfloat16(h), q1 = __float2bfloat16(h1);
      __hip_bfloat16 q2 = __float2bfloat16(h2), q3 = __float2bfloat16(h3);
      unsigned long long v = (unsigned long long)*(uint16_t*)&q0
                           | ((unsigned long long)*(uint16_t*)&q1 << 16)
                           | ((unsigned long long)*(uint16_t*)&q2 << 32)
                           | ((unsigned long long)*(uint16_t*)&q3 << 48);
      __hip_atomic_store(&Hq[(size_t)t * 8192 + pubw], v,
                         __ATOMIC_RELAXED, __HIP_MEMORY_SCOPE_AGENT);
    }

    if (t == NSTEP - 1) break;

    // poll H[t] with NEED bitmask: 32 words/thread first pass, only missing afterwards
    {
      const unsigned long long* src = Hq + (size_t)t * 8192;
      uint32_t need = 0xFFFFFFFFu;
      for (;;) {
        #pragma unroll
        for (int j = 0; j < 32; ++j) {
          if (need & (1u << j)) {
            unsigned long long v = __hip_atomic_load(&src[j * 256 + tid],
                                     __ATOMIC_RELAXED, __HIP_MEMORY_SCOPE_AGENT);
            if (v != SENT) {
              int off = (((tid >> 1) ^ (j & 7)) << 3) + ((tid & 1) << 2);
              *(uint2*)&hbuf[j * 1024 + off] = *(uint2*)&v;
              need &= ~(1u << j);
            }
          }
        }
        if (need == 0) break;
        __builtin_amdgcn_s_sleep(1);
      }
    }
    __syncthreads();   // S2
  }
}

// ---------------- logits GEMM: 256x256, asymmetric-depth pipeline ----------------
// A (L2-resident H): 2 buffers, depth-1. B (L3-resident WT): 3 buffers, depth-2.
// FIFO-counted vmcnt(4) waits exactly {A(kt),B(kt)}; B(kt+1) stays in flight.
// One barrier per iteration; setprio around MFMA cluster. LDS = 160 KB.
__global__ __launch_bounds__(512, 1) void k_gemm(
    const __hip_bfloat16* __restrict__ H,    // [3200][1024] (rows 3168..3199 zero)
    const __hip_bfloat16* __restrict__ WT,   // [32000][1024]
    const float* __restrict__ b_lm,
    float* __restrict__ out) {
  extern __shared__ char glds[];
  __hip_bfloat16* As = (__hip_bfloat16*)glds;            // [2][256*64] = 64 KB
  __hip_bfloat16* Bs = (__hip_bfloat16*)(glds + 65536);  // [3][256*64] = 96 KB

  // XCD-bijective remap: nwg = 1625 = 8*203 + 1
  int bid = blockIdx.x;
  int xcd = bid & 7;
  int idx = bid >> 3;
  int wg = (xcd < 1 ? xcd * 204 : 204 + (xcd - 1) * 203) + idx;
  // grouped raster: groups of GM=4 m-tiles, mt fastest within group (13 = 4+4+4+1)
  int group = wg / 500;                       // 0..3
  int u = wg - group * 500;
  int gm = (group == 3) ? 1 : 4;
  int mt = group * 4 + (u % gm);              // 0..12
  int nt = u / gm;                            // 0..124
  const int mbase = mt * 256;
  const int nbase = nt * 256;

  const int tid = threadIdx.x;
  const int lane = tid & 63;
  const int wid = tid >> 6;      // 0..7
  const int wm = wid >> 2;       // 0..1  (M 128-half)
  const int wn = wid & 3;        // 0..3  (N 64-quarter)

  f32x4 acc[8][4];
  #pragma unroll
  for (int m = 0; m < 8; ++m)
    #pragma unroll
    for (int n = 0; n < 4; ++n) acc[m][n] = (f32x4){0.f, 0.f, 0.f, 0.f};

  const int kg = lane >> 4;

  int srowA[4], srowB[4], soff[4];
  #pragma unroll
  for (int j = 0; j < 4; ++j) {
    int c = j * 512 + tid;
    int row = c >> 3;
    srowB[j] = nbase + row;
    srowA[j] = min(mbase + row, MPAD - 1);   // clamp pad rows (zeros)
    soff[j] = ((c & 7) ^ (row & 7)) * 8;
  }
  const int ldsbase = (tid & 448) * 8;

  auto SA = [&](int s, int kt) {
    #pragma unroll
    for (int j = 0; j < 4; ++j)
      gload_lds16(H + (size_t)srowA[j] * 1024 + kt * 64 + soff[j],
                  As + s * 16384 + j * 4096 + ldsbase);
  };
  auto SB = [&](int s, int kt) {
    #pragma unroll
    for (int j = 0; j < 4; ++j)
      gload_lds16(WT + (size_t)srowB[j] * 1024 + kt * 64 + soff[j],
                  Bs + s * 16384 + j * 4096 + ldsbase);
  };
  auto COMPUTE = [&](int sa, int sb) {
    #pragma unroll
    for (int kk = 0; kk < 2; ++kk) {
      const int slot = kk * 4 + kg;
      short8 a[8], b[4];
      #pragma unroll
      for (int m = 0; m < 8; ++m) {
        int r = wm * 128 + m * 16 + (lane & 15);
        a[m] = *(const short8*)&As[sa * 16384 + r * 64 + ((slot ^ (r & 7)) << 3)];
      }
      #pragma unroll
      for (int n = 0; n < 4; ++n) {
        int r = wn * 64 + n * 16 + (lane & 15);
        b[n] = *(const short8*)&Bs[sb * 16384 + r * 64 + ((slot ^ (r & 7)) << 3)];
      }
      #pragma unroll
      for (int m = 0; m < 8; ++m)
        #pragma unroll
        for (int n = 0; n < 4; ++n)
          acc[m][n] = __builtin_amdgcn_mfma_f32_16x16x32_bf16(a[m], b[n], acc[m][n], 0, 0, 0);
    }
  };

  // prologue FIFO: A0(4), B0(4), B1(4)
  SA(0, 0);
  SB(0, 0);
  SB(1, 1);
  for (int kt = 0; kt < 16; ++kt) {
    if (kt < 15) asm volatile("s_waitcnt vmcnt(4)" ::: "memory");  // A(kt)+B(kt) done; B(kt+1) in flight
    else         asm volatile("s_waitcnt vmcnt(0)" ::: "memory");
    __builtin_amdgcn_s_barrier();            // all waves: loads landed + prev compute done
    if (kt + 1 < 16) SA((kt + 1) & 1, kt + 1);
    if (kt + 2 < 16) SB((kt + 2) % 3, kt + 2);
    __builtin_amdgcn_sched_barrier(0);
    __builtin_amdgcn_s_setprio(1);
    COMPUTE(kt & 1, kt % 3);
    __builtin_amdgcn_s_setprio(0);
    __builtin_amdgcn_sched_barrier(0);
  }

  #pragma unroll
  for (int n = 0; n < 4; ++n) {
    int gcol = nbase + wn * 64 + n * 16 + (lane & 15);
    float bl = b_lm[gcol];
    #pragma unroll
    for (int m = 0; m < 8; ++m) {
      int rbase = mbase + wm * 128 + m * 16 + ((lane >> 4) << 2);
      #pragma unroll
      for (int q = 0; q < 4; ++q) {
        int r = rbase + q;
        if (r < MROWS)
          out[(size_t)(r + 32) * V_ + gcol] = acc[m][n][q] + bl;
      }
    }
  }
}

extern "C" void kernel_launch(void* const* d_in, const int* in_sizes, int n_in,
                              void* d_out, int out_size, void* d_ws, size_t ws_size,
                              hipStream_t stream) {
  const float* features = (const float*)d_in[0];
  // d_in[1]=W_fk, d_in[2]=b_fk, d_in[5]=W_tk, d_in[6]=b_tk : dead code (softmax over size-1 axis)
  const float* W_fv = (const float*)d_in[3];
  const float* b_fv = (const float*)d_in[4];
  const float* W_ih = (const float*)d_in[7];
  const float* W_hh = (const float*)d_in[8];
  const float* b_ih = (const float*)d_in[9];
  const float* b_hh = (const float*)d_in[10];
  const float* W_lm = (const float*)d_in[11];
  const float* b_lm = (const float*)d_in[12];
  const float* bos  = (const float*)d_in[13];
  float* out = (float*)d_out;
  char* ws = (char*)d_ws;

  __hip_bfloat16* WT     = (__hip_bfloat16*)(ws + OFF_WT);
  __hip_bfloat16* H      = (__hip_bfloat16*)(ws + OFF_H);
  unsigned long long* Hq = (unsigned long long*)(ws + OFF_H);
  float* fsum            = (float*)(ws + OFF_FSUM);
  float* ctx             = (float*)(ws + OFF_CTX);
  float* gbase           = (float*)(ws + OFF_GBASE);

  hipLaunchKernelGGL(k_init,  dim3(792),    dim3(256), 0, stream, Hq);
  hipLaunchKernelGGL(k_fsum,  dim3(128),    dim3(256), 0, stream, features, fsum);
  hipLaunchKernelGGL(k_ctx,   dim3(16, 2),  dim3(256), 0, stream, fsum, W_fv, b_fv, ctx);
  hipLaunchKernelGGL(k_gbase, dim3(16, 2),  dim3(256), 0, stream, ctx, W_ih, b_ih, b_hh, gbase);
  // blocks 0..127: recurrence; 128..255: one-hot + pad zero + W_lm->WT (concurrent)
  hipLaunchKernelGGL(k_rec,   dim3(256),  dim3(256), 135296, stream,
                     gbase, W_hh, bos, Hq, W_lm, WT, out);
  hipLaunchKernelGGL(k_gemm,  dim3(1625), dim3(512), 163840, stream, H, WT, b_lm, out);
}

// Round 12
// 1043.066 us; speedup vs baseline: 1.6587x; 1.6587x over previous
//
#include <hip/hip_runtime.h>
#include <hip/hip_bf16.h>
#include <stdint.h>

typedef __attribute__((ext_vector_type(8))) short short8;
typedef __attribute__((ext_vector_type(4))) float f32x4;

#define B_ 32
#define N_ 196
#define D_ 1024
#define V_ 32000
#define NSTEP 99
#define MROWS 3168   // 99*32
#define MPAD  3200
#define SENT  0x7FC07FC07FC07FC0ULL   // 4x bf16 NaN: unreachable as packed h (|h|<1)

// workspace layout (bytes)
#define OFF_WT    0ULL          // bf16 [32000][1024]  = 65,536,000
#define OFF_H     65536000ULL   // bf16 [3200][1024]   =  6,553,600  (u64 view: [99][8192] + pad rows)
#define OFF_FSUM  72089600ULL   // f32  [32][1024]
#define OFF_CTX   72220672ULL   // f32  [32][1024]
#define OFF_GBASE 72351744ULL   // f32  [32][4096]

#define AS3 __attribute__((address_space(3)))
#define AS1 __attribute__((address_space(1)))
static __device__ __forceinline__ void gload_lds16(const void* g, void* l) {
  __builtin_amdgcn_global_load_lds((const AS1 uint32_t*)g, (AS3 uint32_t*)l, 16, 0, 0);
}

// ---------------- sentinel-fill H[0..99) steps (u64 view) ----------------
__global__ void k_init(unsigned long long* __restrict__ Hq) {
  int base = (blockIdx.x * 256 + threadIdx.x) * 4;   // grid 792 -> 811,008 words
  #pragma unroll
  for (int j = 0; j < 4; ++j) Hq[base + j] = SENT;
}

// ---------------- fsum[b,e] = sum_n relu(features[b,n,e]) ----------------
__global__ void k_fsum(const float* __restrict__ feat, float* __restrict__ fsum) {
  int idx = blockIdx.x * 256 + threadIdx.x;           // 32768
  int b = idx >> 10, e = idx & 1023;
  const float* p = feat + (size_t)b * (N_ * D_) + e;
  float s = 0.f;
  #pragma unroll 4
  for (int n = 0; n < N_; ++n) s += fmaxf(p[(size_t)n * D_], 0.f);
  fsum[idx] = s;
}

// ---------------- ctx = fsum @ W_fv + 196*b_fv  (16-batch LDS, W_fv read 2x) ----------------
__global__ void k_ctx(const float* __restrict__ fsum, const float* __restrict__ W_fv,
                      const float* __restrict__ b_fv, float* __restrict__ ctx) {
  __shared__ float fs[16][1024];                      // 64 KB
  int b0 = blockIdx.y * 16;                           // grid (16,2)
  int d = blockIdx.x * 64 + (threadIdx.x & 63);
  int bq = threadIdx.x >> 6;                          // 4 batch-quads
  for (int i = threadIdx.x; i < 16384; i += 256)
    fs[i >> 10][i & 1023] = fsum[(b0 + (i >> 10)) * 1024 + (i & 1023)];
  __syncthreads();
  float bias = 196.f * b_fv[d];
  float acc[4] = {bias, bias, bias, bias};
  for (int e4 = 0; e4 < 256; ++e4) {
    float w0 = W_fv[(size_t)(4 * e4 + 0) * 1024 + d];
    float w1 = W_fv[(size_t)(4 * e4 + 1) * 1024 + d];
    float w2 = W_fv[(size_t)(4 * e4 + 2) * 1024 + d];
    float w3 = W_fv[(size_t)(4 * e4 + 3) * 1024 + d];
    #pragma unroll
    for (int r = 0; r < 4; ++r) {
      float4 c = *(const float4*)&fs[bq * 4 + r][e4 * 4];
      acc[r] = fmaf(c.x, w0, fmaf(c.y, w1, fmaf(c.z, w2, fmaf(c.w, w3, acc[r]))));
    }
  }
  #pragma unroll
  for (int r = 0; r < 4; ++r) ctx[(size_t)(b0 + bq * 4 + r) * 1024 + d] = acc[r];
}

// ---------------- gbase = ctx @ W_ih + b_ih + b_hh  (16-batch LDS, W_ih read 2x) ----------------
__global__ void k_gbase(const float* __restrict__ ctx, const float* __restrict__ W_ih,
                        const float* __restrict__ b_ih, const float* __restrict__ b_hh,
                        float* __restrict__ gbase) {
  __shared__ float cs[16][1024];                      // 64 KB
  int b0 = blockIdx.y * 16;                           // grid (16,2)
  int j = blockIdx.x * 256 + threadIdx.x;
  for (int i = threadIdx.x; i < 16384; i += 256)
    cs[i >> 10][i & 1023] = ctx[(size_t)(b0 + (i >> 10)) * 1024 + (i & 1023)];
  __syncthreads();
  float bias = b_ih[j] + b_hh[j];
  float acc[16];
  #pragma unroll
  for (int r = 0; r < 16; ++r) acc[r] = bias;
  for (int e4 = 0; e4 < 256; ++e4) {
    float w0 = W_ih[(size_t)(4 * e4 + 0) * 4096 + j];
    float w1 = W_ih[(size_t)(4 * e4 + 1) * 4096 + j];
    float w2 = W_ih[(size_t)(4 * e4 + 2) * 4096 + j];
    float w3 = W_ih[(size_t)(4 * e4 + 3) * 4096 + j];
    #pragma unroll
    for (int r = 0; r < 16; ++r) {
      float4 c = *(const float4*)&cs[r][e4 * 4];
      acc[r] = fmaf(c.x, w0, fmaf(c.y, w1, fmaf(c.z, w2, fmaf(c.w, w3, acc[r]))));
    }
  }
  #pragma unroll
  for (int r = 0; r < 16; ++r) gbase[(size_t)(b0 + r) * 4096 + j] = acc[r];
}

// ---------------- persistent LSTM recurrence (blocks 0..127) + workers (128..255) ----------------
// 2-D decomposition: block (bh,dg) owns batches bh*16..+16 and h-dims dg*16..+16 (64 gate
// cols). Sentinel-payload exchange into H[t]; consumer polls only its 16 batch rows
// (32 KB/step, 16 words/thread, unconditional batched loads).
__global__ __launch_bounds__(256, 1) void k_rec(
    const float* __restrict__ gbase, const float* __restrict__ W_hh,
    const float* __restrict__ bos, unsigned long long* __restrict__ Hq,
    const float* __restrict__ W_lm, __hip_bfloat16* __restrict__ WT,
    float* __restrict__ out) {
  extern __shared__ char lds[];
  const int tid = threadIdx.x;
  const int blk = blockIdx.x;

  if (blk >= 128) {
    // ---------- worker blocks ----------
    __hip_bfloat16* t = (__hip_bfloat16*)lds;          // [64][66]
    int wblk = blk - 128;
    for (int idx = wblk * 256 + tid; idx < B_ * V_; idx += 128 * 256)
      out[idx] = ((idx % V_) == 0) ? 1.0f : 0.0f;
    // zero TRUE pad rows 3168..3199 (256 u64 per row)
    if (wblk < 64) ((uint32_t*)(Hq + (size_t)MROWS * 256))[wblk * 256 + tid] = 0u;
    int tx = tid & 63, ty = tid >> 6;
    int word = tx & 31, nh = tx >> 5;
    for (int tile = wblk; tile < 8000; tile += 128) {
      int k0 = (tile & 15) * 64;
      int n0 = (tile >> 4) * 64;
      __syncthreads();
      #pragma unroll
      for (int i = 0; i < 16; ++i) {
        int r = i * 4 + ty;
        t[r * 66 + tx] = __float2bfloat16(W_lm[(size_t)(k0 + r) * V_ + n0 + tx]);
      }
      __syncthreads();
      #pragma unroll
      for (int i = 0; i < 8; ++i) {
        int n = i * 8 + ty * 2 + nh;
        uint32_t lo = *(const uint16_t*)&t[2 * word * 66 + n];
        uint32_t hi = *(const uint16_t*)&t[(2 * word + 1) * 66 + n];
        ((uint32_t*)&WT[(size_t)(n0 + n) * 1024 + k0])[word] = lo | (hi << 16);
      }
    }
    return;
  }

  // ---------- recurrence blocks ----------
  __hip_bfloat16* hbuf = (__hip_bfloat16*)lds;             // [16][1024] swizzled (32 KB)
  __hip_bfloat16* wbuf = (__hip_bfloat16*)(lds + 32768);   // [64][1024] (init only, 128 KB)
  float* gex = (float*)(lds + 32768);                      // [16][68] f32, aliases wbuf

  const int bh = blk >> 6;     // batch half 0..1
  const int dg = blk & 63;     // dim group 0..63 (dims dg*16..+16)

  // stage W_hh slice: local col c = g*16+dl -> global col g*1024 + dg*16 + dl
  for (int idx = tid; idx < 64 * 1024; idx += 256) {
    int c = idx & 63;
    int k = idx >> 6;
    float w = W_hh[(size_t)k * 4096 + (c >> 4) * 1024 + dg * 16 + (c & 15)];
    wbuf[c * 1024 + ((((k >> 3) ^ (c & 7)) << 3) | (k & 7))] = __float2bfloat16(w);
  }
  // h0 = bos broadcast to local 16 batch rows
  for (int idx = tid; idx < 16 * 1024; idx += 256) {
    int row = idx >> 10;
    int k = idx & 1023;
    hbuf[row * 1024 + ((((k >> 3) ^ (row & 7)) << 3) | (k & 7))] = __float2bfloat16(bos[k]);
  }

  const int btl = tid >> 4;    // local batch 0..15
  const int dl = tid & 15;     // local dim 0..15
  const size_t gbrow = (size_t)(bh * 16 + btl) * 4096 + dg * 16 + dl;
  float gb0 = gbase[gbrow + 0 * 1024];
  float gb1 = gbase[gbrow + 1 * 1024];
  float gb2 = gbase[gbrow + 2 * 1024];
  float gb3 = gbase[gbrow + 3 * 1024];
  float cst = 0.f;

  const int lane = tid & 63;
  const int wid = tid >> 6;          // 0..3 : wave owns local cols wid*16..+16
  const int arow = lane & 15;        // batch row (single 16-row tile)
  const int bcol = wid * 16 + (lane & 15);
  const int kg = lane >> 4;
  const int axor = arow & 7;

  __syncthreads();

  // W_hh B-fragments -> registers (unconditional per-wave; 32 x short8 = 128 VGPR)
  short8 breg[32];
  #pragma unroll
  for (int kt = 0; kt < 32; ++kt) {
    int ca = kt * 4 + kg;
    breg[kt] = *(const short8*)&wbuf[bcol * 1024 + ((ca ^ (bcol & 7)) << 3)];
  }

  const int pubw = (bh * 16 + btl) * 256 + dg * 4 + (dl >> 2);

  for (int t = 0; t < NSTEP; ++t) {
    // gates[16 local batches x 64 local cols] = h @ Wslice (4 waves x 1 tile, B in regs)
    f32x4 acc0 = {0.f, 0.f, 0.f, 0.f};
    f32x4 acc1 = {0.f, 0.f, 0.f, 0.f};
    #pragma unroll
    for (int kt = 0; kt < 32; kt += 2) {
      int ca = kt * 4 + kg;
      short8 a0 = *(const short8*)&hbuf[arow * 1024 + ((ca ^ axor) << 3)];
      acc0 = __builtin_amdgcn_mfma_f32_16x16x32_bf16(a0, breg[kt], acc0, 0, 0, 0);
      short8 a1 = *(const short8*)&hbuf[arow * 1024 + (((ca + 4) ^ axor) << 3)];
      acc1 = __builtin_amdgcn_mfma_f32_16x16x32_bf16(a1, breg[kt + 1], acc1, 0, 0, 0);
    }
    acc0 = acc0 + acc1;
    __syncthreads();   // hbuf reads done; gex (aliases nothing live) safe after S of prev step
    {
      int bq = (lane >> 4) << 2;
      #pragma unroll
      for (int q = 0; q < 4; ++q) gex[(bq + q) * 68 + bcol] = acc0[q];
    }
    __syncthreads();   // S1: gex written

    float gi = gex[btl * 68 + 0  + dl] + gb0;
    float gf = gex[btl * 68 + 16 + dl] + gb1;
    float gg = gex[btl * 68 + 32 + dl] + gb2;
    float go = gex[btl * 68 + 48 + dl] + gb3;
    float si = 1.f / (1.f + __expf(-gi));
    float sf = 1.f / (1.f + __expf(-gf));
    float so = 1.f / (1.f + __expf(-go));
    cst = sf * cst + si * tanhf(gg);
    float h = so * tanhf(cst);

    // publish packed 4x bf16 into H[t] (one u64 per 4 dims)
    float h1 = __shfl_down(h, 1);
    float h2 = __shfl_down(h, 2);
    float h3 = __shfl_down(h, 3);
    if ((dl & 3) == 0) {
      __hip_bfloat16 q0 = __float2bfloat16(h), q1 = __float2bfloat16(h1);
      __hip_bfloat16 q2 = __float2bfloat16(h2), q3 = __float2bfloat16(h3);
      unsigned long long v = (unsigned long long)*(uint16_t*)&q0
                           | ((unsigned long long)*(uint16_t*)&q1 << 16)
                           | ((unsigned long long)*(uint16_t*)&q2 << 32)
                           | ((unsigned long long)*(uint16_t*)&q3 << 48);
      __hip_atomic_store(&Hq[(size_t)t * 8192 + pubw], v,
                         __ATOMIC_RELAXED, __HIP_MEMORY_SCOPE_AGENT);
    }

    if (t == NSTEP - 1) break;

    // poll own 16 batch rows of H[t]: 16 words/thread, unconditional batched loads
    {
      const unsigned long long* src = Hq + (size_t)t * 8192 + (size_t)bh * 16 * 256;
      for (;;) {
        unsigned long long v[16];
        #pragma unroll
        for (int j = 0; j < 16; ++j)
          v[j] = __hip_atomic_load(&src[j * 256 + tid],
                                   __ATOMIC_RELAXED, __HIP_MEMORY_SCOPE_AGENT);
        int nready = 0;
        #pragma unroll
        for (int j = 0; j < 16; ++j) {
          if (v[j] != SENT) {
            int off = (((tid >> 1) ^ (j & 7)) << 3) + ((tid & 1) << 2);
            *(uint2*)&hbuf[j * 1024 + off] = *(uint2*)&v[j];
            ++nready;
          }
        }
        if (nready == 16) break;
        __builtin_amdgcn_s_sleep(1);
      }
    }
    __syncthreads();   // S2: hbuf fully deposited
  }
}

// ---------------- logits GEMM (round-7/10 validated): 256x256, 2-stage dbuf, vmcnt(8) ----------------
__global__ __launch_bounds__(512, 1) void k_gemm(
    const __hip_bfloat16* __restrict__ H,    // [3200][1024] (rows 3168..3199 zero)
    const __hip_bfloat16* __restrict__ WT,   // [32000][1024]
    const float* __restrict__ b_lm,
    float* __restrict__ out) {
  extern __shared__ char glds[];
  __hip_bfloat16* As = (__hip_bfloat16*)glds;            // [2][256*64] = 64 KB
  __hip_bfloat16* Bs = (__hip_bfloat16*)(glds + 65536);  // [2][256*64] = 64 KB

  // XCD-bijective remap: nwg = 1625 = 8*203 + 1
  int bid = blockIdx.x;
  int xcd = bid & 7;
  int idx = bid >> 3;
  int wg = (xcd < 1 ? xcd * 204 : 204 + (xcd - 1) * 203) + idx;
  // grouped raster: groups of GM=4 m-tiles, mt fastest within group (13 = 4+4+4+1)
  int group = wg / 500;                       // 0..3
  int u = wg - group * 500;
  int gm = (group == 3) ? 1 : 4;
  int mt = group * 4 + (u % gm);              // 0..12
  int nt = u / gm;                            // 0..124
  const int mbase = mt * 256;
  const int nbase = nt * 256;

  const int tid = threadIdx.x;
  const int lane = tid & 63;
  const int wid = tid >> 6;      // 0..7
  const int wm = wid >> 2;       // 0..1  (M 128-half)
  const int wn = wid & 3;        // 0..3  (N 64-quarter)

  f32x4 acc[8][4];
  #pragma unroll
  for (int m = 0; m < 8; ++m)
    #pragma unroll
    for (int n = 0; n < 4; ++n) acc[m][n] = (f32x4){0.f, 0.f, 0.f, 0.f};

  const int kg = lane >> 4;

  int srowA[4], srowB[4], soff[4];
  #pragma unroll
  for (int j = 0; j < 4; ++j) {
    int c = j * 512 + tid;
    int row = c >> 3;
    srowB[j] = nbase + row;
    srowA[j] = min(mbase + row, MPAD - 1);   // clamp pad rows (zeros)
    soff[j] = ((c & 7) ^ (row & 7)) * 8;
  }
  const int ldsbase = (tid & 448) * 8;

  auto STAGE = [&](int nb, int kt) {
    #pragma unroll
    for (int j = 0; j < 4; ++j)
      gload_lds16(H + (size_t)srowA[j] * 1024 + kt * 64 + soff[j],
                  As + nb * 16384 + j * 4096 + ldsbase);
    #pragma unroll
    for (int j = 0; j < 4; ++j)
      gload_lds16(WT + (size_t)srowB[j] * 1024 + kt * 64 + soff[j],
                  Bs + nb * 16384 + j * 4096 + ldsbase);
  };
  auto COMPUTE = [&](int nb) {
    #pragma unroll
    for (int kk = 0; kk < 2; ++kk) {
      const int slot = kk * 4 + kg;
      short8 a[8], b[4];
      #pragma unroll
      for (int m = 0; m < 8; ++m) {
        int r = wm * 128 + m * 16 + (lane & 15);
        a[m] = *(const short8*)&As[nb * 16384 + r * 64 + ((slot ^ (r & 7)) << 3)];
      }
      #pragma unroll
      for (int n = 0; n < 4; ++n) {
        int r = wn * 64 + n * 16 + (lane & 15);
        b[n] = *(const short8*)&Bs[nb * 16384 + r * 64 + ((slot ^ (r & 7)) << 3)];
      }
      #pragma unroll
      for (int m = 0; m < 8; ++m)
        #pragma unroll
        for (int n = 0; n < 4; ++n)
          acc[m][n] = __builtin_amdgcn_mfma_f32_16x16x32_bf16(a[m], b[n], acc[m][n], 0, 0, 0);
    }
  };

  STAGE(0, 0);
  for (int kt = 0; kt < 15; ++kt) {
    STAGE((kt + 1) & 1, kt + 1);
    asm volatile("s_waitcnt vmcnt(8)" ::: "memory");
    __builtin_amdgcn_s_barrier();
    __builtin_amdgcn_sched_barrier(0);
    COMPUTE(kt & 1);
    __builtin_amdgcn_sched_barrier(0);
    __builtin_amdgcn_s_barrier();
  }
  asm volatile("s_waitcnt vmcnt(0)" ::: "memory");
  __builtin_amdgcn_s_barrier();
  __builtin_amdgcn_sched_barrier(0);
  COMPUTE(1);

  #pragma unroll
  for (int n = 0; n < 4; ++n) {
    int gcol = nbase + wn * 64 + n * 16 + (lane & 15);
    float bl = b_lm[gcol];
    #pragma unroll
    for (int m = 0; m < 8; ++m) {
      int rbase = mbase + wm * 128 + m * 16 + ((lane >> 4) << 2);
      #pragma unroll
      for (int q = 0; q < 4; ++q) {
        int r = rbase + q;
        if (r < MROWS)
          out[(size_t)(r + 32) * V_ + gcol] = acc[m][n][q] + bl;
      }
    }
  }
}

extern "C" void kernel_launch(void* const* d_in, const int* in_sizes, int n_in,
                              void* d_out, int out_size, void* d_ws, size_t ws_size,
                              hipStream_t stream) {
  const float* features = (const float*)d_in[0];
  // d_in[1]=W_fk, d_in[2]=b_fk, d_in[5]=W_tk, d_in[6]=b_tk : dead code (softmax over size-1 axis)
  const float* W_fv = (const float*)d_in[3];
  const float* b_fv = (const float*)d_in[4];
  const float* W_ih = (const float*)d_in[7];
  const float* W_hh = (const float*)d_in[8];
  const float* b_ih = (const float*)d_in[9];
  const float* b_hh = (const float*)d_in[10];
  const float* W_lm = (const float*)d_in[11];
  const float* b_lm = (const float*)d_in[12];
  const float* bos  = (const float*)d_in[13];
  float* out = (float*)d_out;
  char* ws = (char*)d_ws;

  __hip_bfloat16* WT     = (__hip_bfloat16*)(ws + OFF_WT);
  __hip_bfloat16* H      = (__hip_bfloat16*)(ws + OFF_H);
  unsigned long long* Hq = (unsigned long long*)(ws + OFF_H);
  float* fsum            = (float*)(ws + OFF_FSUM);
  float* ctx             = (float*)(ws + OFF_CTX);
  float* gbase           = (float*)(ws + OFF_GBASE);

  hipLaunchKernelGGL(k_init,  dim3(792),    dim3(256), 0, stream, Hq);
  hipLaunchKernelGGL(k_fsum,  dim3(128),    dim3(256), 0, stream, features, fsum);
  hipLaunchKernelGGL(k_ctx,   dim3(16, 2),  dim3(256), 0, stream, fsum, W_fv, b_fv, ctx);
  hipLaunchKernelGGL(k_gbase, dim3(16, 2),  dim3(256), 0, stream, ctx, W_ih, b_ih, b_hh, gbase);
  // blocks 0..127: recurrence; 128..255: one-hot + pad zero + W_lm->WT (concurrent)
  hipLaunchKernelGGL(k_rec,   dim3(256),  dim3(256), 163840, stream,
                     gbase, W_hh, bos, Hq, W_lm, WT, out);
  hipLaunchKernelGGL(k_gemm,  dim3(1625), dim3(512), 131072, stream, H, WT, b_lm, out);
}

// Round 13
// 888.531 us; speedup vs baseline: 1.9472x; 1.1739x over previous
//
#include <hip/hip_runtime.h>
#include <hip/hip_bf16.h>
#include <stdint.h>

typedef __attribute__((ext_vector_type(8))) short short8;
typedef __attribute__((ext_vector_type(4))) float f32x4;

#define B_ 32
#define N_ 196
#define D_ 1024
#define V_ 32000
#define NSTEP 99
#define MROWS 3168   // 99*32
#define MPAD  3200
#define SENT  0x7FC07FC07FC07FC0ULL   // 4x bf16 NaN: unreachable as packed h (|h|<1)

// workspace layout (bytes)
#define OFF_WT    0ULL          // bf16 [32000][1024]  = 65,536,000
#define OFF_H     65536000ULL   // bf16 [3200][1024]   =  6,553,600  (u64 view: [99][8192] + pad rows)
#define OFF_FSUM  72089600ULL   // f32  [32][1024]
#define OFF_CTX   72220672ULL   // f32  [32][1024]
#define OFF_GBASE 72351744ULL   // f32  [32][4096]

#define AS3 __attribute__((address_space(3)))
#define AS1 __attribute__((address_space(1)))
static __device__ __forceinline__ void gload_lds16(const void* g, void* l) {
  __builtin_amdgcn_global_load_lds((const AS1 uint32_t*)g, (AS3 uint32_t*)l, 16, 0, 0);
}

// ---------------- fsum (blocks 0..127) + sentinel-fill H (blocks 128..383) ----------------
__global__ void k_fsum(const float* __restrict__ feat, float* __restrict__ fsum,
                       unsigned long long* __restrict__ Hq) {
  if (blockIdx.x >= 128) {
    int gid = (blockIdx.x - 128) * 256 + threadIdx.x;   // 65536 threads
    for (int w = gid; w < NSTEP * 8192; w += 65536) Hq[w] = SENT;
    return;
  }
  int idx = blockIdx.x * 256 + threadIdx.x;           // 32768
  int b = idx >> 10, e = idx & 1023;
  const float* p = feat + (size_t)b * (N_ * D_) + e;
  float s = 0.f;
  #pragma unroll 4
  for (int n = 0; n < N_; ++n) s += fmaxf(p[(size_t)n * D_], 0.f);
  fsum[idx] = s;
}

// ---------------- ctx = fsum @ W_fv + 196*b_fv  (16-batch LDS, W_fv read 2x) ----------------
__global__ void k_ctx(const float* __restrict__ fsum, const float* __restrict__ W_fv,
                      const float* __restrict__ b_fv, float* __restrict__ ctx) {
  __shared__ float fs[16][1024];                      // 64 KB
  int b0 = blockIdx.y * 16;                           // grid (16,2)
  int d = blockIdx.x * 64 + (threadIdx.x & 63);
  int bq = threadIdx.x >> 6;                          // 4 batch-quads
  for (int i = threadIdx.x; i < 16384; i += 256)
    fs[i >> 10][i & 1023] = fsum[(b0 + (i >> 10)) * 1024 + (i & 1023)];
  __syncthreads();
  float bias = 196.f * b_fv[d];
  float acc[4] = {bias, bias, bias, bias};
  for (int e4 = 0; e4 < 256; ++e4) {
    float w0 = W_fv[(size_t)(4 * e4 + 0) * 1024 + d];
    float w1 = W_fv[(size_t)(4 * e4 + 1) * 1024 + d];
    float w2 = W_fv[(size_t)(4 * e4 + 2) * 1024 + d];
    float w3 = W_fv[(size_t)(4 * e4 + 3) * 1024 + d];
    #pragma unroll
    for (int r = 0; r < 4; ++r) {
      float4 c = *(const float4*)&fs[bq * 4 + r][e4 * 4];
      acc[r] = fmaf(c.x, w0, fmaf(c.y, w1, fmaf(c.z, w2, fmaf(c.w, w3, acc[r]))));
    }
  }
  #pragma unroll
  for (int r = 0; r < 4; ++r) ctx[(size_t)(b0 + bq * 4 + r) * 1024 + d] = acc[r];
}

// ---------------- gbase = ctx @ W_ih + b_ih + b_hh  (16-batch LDS, W_ih read 2x) ----------------
__global__ void k_gbase(const float* __restrict__ ctx, const float* __restrict__ W_ih,
                        const float* __restrict__ b_ih, const float* __restrict__ b_hh,
                        float* __restrict__ gbase) {
  __shared__ float cs[16][1024];                      // 64 KB
  int b0 = blockIdx.y * 16;                           // grid (16,2)
  int j = blockIdx.x * 256 + threadIdx.x;
  for (int i = threadIdx.x; i < 16384; i += 256)
    cs[i >> 10][i & 1023] = ctx[(size_t)(b0 + (i >> 10)) * 1024 + (i & 1023)];
  __syncthreads();
  float bias = b_ih[j] + b_hh[j];
  float acc[16];
  #pragma unroll
  for (int r = 0; r < 16; ++r) acc[r] = bias;
  for (int e4 = 0; e4 < 256; ++e4) {
    float w0 = W_ih[(size_t)(4 * e4 + 0) * 4096 + j];
    float w1 = W_ih[(size_t)(4 * e4 + 1) * 4096 + j];
    float w2 = W_ih[(size_t)(4 * e4 + 2) * 4096 + j];
    float w3 = W_ih[(size_t)(4 * e4 + 3) * 4096 + j];
    #pragma unroll
    for (int r = 0; r < 16; ++r) {
      float4 c = *(const float4*)&cs[r][e4 * 4];
      acc[r] = fmaf(c.x, w0, fmaf(c.y, w1, fmaf(c.z, w2, fmaf(c.w, w3, acc[r]))));
    }
  }
  #pragma unroll
  for (int r = 0; r < 16; ++r) gbase[(size_t)(b0 + r) * 4096 + j] = acc[r];
}

// ---------------- persistent LSTM recurrence (blocks 0..127) + workers (128..255) ----------------
// 2-D decomposition (round-12 validated): block (bh,dg) owns 16 batches x 16 dims.
// Workers use NONTEMPORAL loads/stores (W_lm stream + WT + one-hot) so the 192 MB convT
// stream doesn't evict the rec exchange lines from the shared per-XCD L2s.
__global__ __launch_bounds__(256, 1) void k_rec(
    const float* __restrict__ gbase, const float* __restrict__ W_hh,
    const float* __restrict__ bos, unsigned long long* __restrict__ Hq,
    const float* __restrict__ W_lm, __hip_bfloat16* __restrict__ WT,
    float* __restrict__ out) {
  extern __shared__ char lds[];
  const int tid = threadIdx.x;
  const int blk = blockIdx.x;

  if (blk >= 128) {
    // ---------- worker blocks ----------
    __hip_bfloat16* t = (__hip_bfloat16*)lds;          // [64][66]
    int wblk = blk - 128;
    for (int idx = wblk * 256 + tid; idx < B_ * V_; idx += 128 * 256)
      __builtin_nontemporal_store(((idx % V_) == 0) ? 1.0f : 0.0f, &out[idx]);
    // zero TRUE pad rows 3168..3199 (256 u64 per row)
    if (wblk < 64) ((uint32_t*)(Hq + (size_t)MROWS * 256))[wblk * 256 + tid] = 0u;
    int tx = tid & 63, ty = tid >> 6;
    int word = tx & 31, nh = tx >> 5;
    for (int tile = wblk; tile < 8000; tile += 128) {
      int k0 = (tile & 15) * 64;
      int n0 = (tile >> 4) * 64;
      __syncthreads();
      #pragma unroll
      for (int i = 0; i < 16; ++i) {
        int r = i * 4 + ty;
        t[r * 66 + tx] = __float2bfloat16(
            __builtin_nontemporal_load(&W_lm[(size_t)(k0 + r) * V_ + n0 + tx]));
      }
      __syncthreads();
      #pragma unroll
      for (int i = 0; i < 8; ++i) {
        int n = i * 8 + ty * 2 + nh;
        uint32_t lo = *(const uint16_t*)&t[2 * word * 66 + n];
        uint32_t hi = *(const uint16_t*)&t[(2 * word + 1) * 66 + n];
        __builtin_nontemporal_store(lo | (hi << 16),
            (uint32_t*)&WT[(size_t)(n0 + n) * 1024 + k0] + word);
      }
    }
    return;
  }

  // ---------- recurrence blocks (round-12 verbatim) ----------
  __hip_bfloat16* hbuf = (__hip_bfloat16*)lds;             // [16][1024] swizzled (32 KB)
  __hip_bfloat16* wbuf = (__hip_bfloat16*)(lds + 32768);   // [64][1024] (init only, 128 KB)
  float* gex = (float*)(lds + 32768);                      // [16][68] f32, aliases wbuf

  const int bh = blk >> 6;     // batch half 0..1
  const int dg = blk & 63;     // dim group 0..63 (dims dg*16..+16)

  for (int idx = tid; idx < 64 * 1024; idx += 256) {
    int c = idx & 63;
    int k = idx >> 6;
    float w = W_hh[(size_t)k * 4096 + (c >> 4) * 1024 + dg * 16 + (c & 15)];
    wbuf[c * 1024 + ((((k >> 3) ^ (c & 7)) << 3) | (k & 7))] = __float2bfloat16(w);
  }
  for (int idx = tid; idx < 16 * 1024; idx += 256) {
    int row = idx >> 10;
    int k = idx & 1023;
    hbuf[row * 1024 + ((((k >> 3) ^ (row & 7)) << 3) | (k & 7))] = __float2bfloat16(bos[k]);
  }

  const int btl = tid >> 4;    // local batch 0..15
  const int dl = tid & 15;     // local dim 0..15
  const size_t gbrow = (size_t)(bh * 16 + btl) * 4096 + dg * 16 + dl;
  float gb0 = gbase[gbrow + 0 * 1024];
  float gb1 = gbase[gbrow + 1 * 1024];
  float gb2 = gbase[gbrow + 2 * 1024];
  float gb3 = gbase[gbrow + 3 * 1024];
  float cst = 0.f;

  const int lane = tid & 63;
  const int wid = tid >> 6;          // 0..3 : wave owns local cols wid*16..+16
  const int arow = lane & 15;        // batch row (single 16-row tile)
  const int bcol = wid * 16 + (lane & 15);
  const int kg = lane >> 4;
  const int axor = arow & 7;

  __syncthreads();

  short8 breg[32];
  #pragma unroll
  for (int kt = 0; kt < 32; ++kt) {
    int ca = kt * 4 + kg;
    breg[kt] = *(const short8*)&wbuf[bcol * 1024 + ((ca ^ (bcol & 7)) << 3)];
  }

  const int pubw = (bh * 16 + btl) * 256 + dg * 4 + (dl >> 2);

  for (int t = 0; t < NSTEP; ++t) {
    f32x4 acc0 = {0.f, 0.f, 0.f, 0.f};
    f32x4 acc1 = {0.f, 0.f, 0.f, 0.f};
    #pragma unroll
    for (int kt = 0; kt < 32; kt += 2) {
      int ca = kt * 4 + kg;
      short8 a0 = *(const short8*)&hbuf[arow * 1024 + ((ca ^ axor) << 3)];
      acc0 = __builtin_amdgcn_mfma_f32_16x16x32_bf16(a0, breg[kt], acc0, 0, 0, 0);
      short8 a1 = *(const short8*)&hbuf[arow * 1024 + (((ca + 4) ^ axor) << 3)];
      acc1 = __builtin_amdgcn_mfma_f32_16x16x32_bf16(a1, breg[kt + 1], acc1, 0, 0, 0);
    }
    acc0 = acc0 + acc1;
    __syncthreads();
    {
      int bq = (lane >> 4) << 2;
      #pragma unroll
      for (int q = 0; q < 4; ++q) gex[(bq + q) * 68 + bcol] = acc0[q];
    }
    __syncthreads();   // S1

    float gi = gex[btl * 68 + 0  + dl] + gb0;
    float gf = gex[btl * 68 + 16 + dl] + gb1;
    float gg = gex[btl * 68 + 32 + dl] + gb2;
    float go = gex[btl * 68 + 48 + dl] + gb3;
    float si = 1.f / (1.f + __expf(-gi));
    float sf = 1.f / (1.f + __expf(-gf));
    float so = 1.f / (1.f + __expf(-go));
    cst = sf * cst + si * tanhf(gg);
    float h = so * tanhf(cst);

    float h1 = __shfl_down(h, 1);
    float h2 = __shfl_down(h, 2);
    float h3 = __shfl_down(h, 3);
    if ((dl & 3) == 0) {
      __hip_bfloat16 q0 = __float2bfloat16(h), q1 = __float2bfloat16(h1);
      __hip_bfloat16 q2 = __float2bfloat16(h2), q3 = __float2bfloat16(h3);
      unsigned long long v = (unsigned long long)*(uint16_t*)&q0
                           | ((unsigned long long)*(uint16_t*)&q1 << 16)
                           | ((unsigned long long)*(uint16_t*)&q2 << 32)
                           | ((unsigned long long)*(uint16_t*)&q3 << 48);
      __hip_atomic_store(&Hq[(size_t)t * 8192 + pubw], v,
                         __ATOMIC_RELAXED, __HIP_MEMORY_SCOPE_AGENT);
    }

    if (t == NSTEP - 1) break;

    {
      const unsigned long long* src = Hq + (size_t)t * 8192 + (size_t)bh * 16 * 256;
      for (;;) {
        unsigned long long v[16];
        #pragma unroll
        for (int j = 0; j < 16; ++j)
          v[j] = __hip_atomic_load(&src[j * 256 + tid],
                                   __ATOMIC_RELAXED, __HIP_MEMORY_SCOPE_AGENT);
        int nready = 0;
        #pragma unroll
        for (int j = 0; j < 16; ++j) {
          if (v[j] != SENT) {
            int off = (((tid >> 1) ^ (j & 7)) << 3) + ((tid & 1) << 2);
            *(uint2*)&hbuf[j * 1024 + off] = *(uint2*)&v[j];
            ++nready;
          }
        }
        if (nready == 16) break;
        __builtin_amdgcn_s_sleep(1);
      }
    }
    __syncthreads();   // S2
  }
}

// ---------------- logits GEMM: 256x256, 2-stage dbuf, vmcnt(8); NT epilogue ----------------
// Nontemporal out-stores keep B panels resident in L2/L3; GM=13 raster reuses each
// B panel across all 13 m-tiles consecutively within an XCD.
__global__ __launch_bounds__(512, 1) void k_gemm(
    const __hip_bfloat16* __restrict__ H,    // [3200][1024] (rows 3168..3199 zero)
    const __hip_bfloat16* __restrict__ WT,   // [32000][1024]
    const float* __restrict__ b_lm,
    float* __restrict__ out) {
  extern __shared__ char glds[];
  __hip_bfloat16* As = (__hip_bfloat16*)glds;            // [2][256*64] = 64 KB
  __hip_bfloat16* Bs = (__hip_bfloat16*)(glds + 65536);  // [2][256*64] = 64 KB

  // XCD-bijective remap: nwg = 1625 = 8*203 + 1
  int bid = blockIdx.x;
  int xcd = bid & 7;
  int idx = bid >> 3;
  int wg = (xcd < 1 ? xcd * 204 : 204 + (xcd - 1) * 203) + idx;
  // GM=13 raster: all 13 m-tiles consecutive per B panel (nt), mt fastest
  int nt = wg / 13;            // 0..124
  int mt = wg - nt * 13;       // 0..12
  const int mbase = mt * 256;
  const int nbase = nt * 256;

  const int tid = threadIdx.x;
  const int lane = tid & 63;
  const int wid = tid >> 6;      // 0..7
  const int wm = wid >> 2;       // 0..1  (M 128-half)
  const int wn = wid & 3;        // 0..3  (N 64-quarter)

  f32x4 acc[8][4];
  #pragma unroll
  for (int m = 0; m < 8; ++m)
    #pragma unroll
    for (int n = 0; n < 4; ++n) acc[m][n] = (f32x4){0.f, 0.f, 0.f, 0.f};

  const int kg = lane >> 4;

  int srowA[4], srowB[4], soff[4];
  #pragma unroll
  for (int j = 0; j < 4; ++j) {
    int c = j * 512 + tid;
    int row = c >> 3;
    srowB[j] = nbase + row;
    srowA[j] = min(mbase + row, MPAD - 1);   // clamp pad rows (zeros)
    soff[j] = ((c & 7) ^ (row & 7)) * 8;
  }
  const int ldsbase = (tid & 448) * 8;

  auto STAGE = [&](int nb, int kt) {
    #pragma unroll
    for (int j = 0; j < 4; ++j)
      gload_lds16(H + (size_t)srowA[j] * 1024 + kt * 64 + soff[j],
                  As + nb * 16384 + j * 4096 + ldsbase);
    #pragma unroll
    for (int j = 0; j < 4; ++j)
      gload_lds16(WT + (size_t)srowB[j] * 1024 + kt * 64 + soff[j],
                  Bs + nb * 16384 + j * 4096 + ldsbase);
  };
  auto COMPUTE = [&](int nb) {
    #pragma unroll
    for (int kk = 0; kk < 2; ++kk) {
      const int slot = kk * 4 + kg;
      short8 a[8], b[4];
      #pragma unroll
      for (int m = 0; m < 8; ++m) {
        int r = wm * 128 + m * 16 + (lane & 15);
        a[m] = *(const short8*)&As[nb * 16384 + r * 64 + ((slot ^ (r & 7)) << 3)];
      }
      #pragma unroll
      for (int n = 0; n < 4; ++n) {
        int r = wn * 64 + n * 16 + (lane & 15);
        b[n] = *(const short8*)&Bs[nb * 16384 + r * 64 + ((slot ^ (r & 7)) << 3)];
      }
      #pragma unroll
      for (int m = 0; m < 8; ++m)
        #pragma unroll
        for (int n = 0; n < 4; ++n)
          acc[m][n] = __builtin_amdgcn_mfma_f32_16x16x32_bf16(a[m], b[n], acc[m][n], 0, 0, 0);
    }
  };

  STAGE(0, 0);
  for (int kt = 0; kt < 15; ++kt) {
    STAGE((kt + 1) & 1, kt + 1);
    asm volatile("s_waitcnt vmcnt(8)" ::: "memory");
    __builtin_amdgcn_s_barrier();
    __builtin_amdgcn_sched_barrier(0);
    COMPUTE(kt & 1);
    __builtin_amdgcn_sched_barrier(0);
    __builtin_amdgcn_s_barrier();
  }
  asm volatile("s_waitcnt vmcnt(0)" ::: "memory");
  __builtin_amdgcn_s_barrier();
  __builtin_amdgcn_sched_barrier(0);
  COMPUTE(1);

  if (mt != 12) {
    #pragma unroll
    for (int n = 0; n < 4; ++n) {
      int gcol = nbase + wn * 64 + n * 16 + (lane & 15);
      float bl = b_lm[gcol];
      #pragma unroll
      for (int m = 0; m < 8; ++m) {
        int rbase = mbase + wm * 128 + m * 16 + ((lane >> 4) << 2);
        #pragma unroll
        for (int q = 0; q < 4; ++q)
          __builtin_nontemporal_store(acc[m][n][q] + bl,
              &out[(size_t)(rbase + q + 32) * V_ + gcol]);
      }
    }
  } else {
    #pragma unroll
    for (int n = 0; n < 4; ++n) {
      int gcol = nbase + wn * 64 + n * 16 + (lane & 15);
      float bl = b_lm[gcol];
      #pragma unroll
      for (int m = 0; m < 8; ++m) {
        int rbase = mbase + wm * 128 + m * 16 + ((lane >> 4) << 2);
        #pragma unroll
        for (int q = 0; q < 4; ++q) {
          int r = rbase + q;
          if (r < MROWS)
            __builtin_nontemporal_store(acc[m][n][q] + bl,
                &out[(size_t)(r + 32) * V_ + gcol]);
        }
      }
    }
  }
}

extern "C" void kernel_launch(void* const* d_in, const int* in_sizes, int n_in,
                              void* d_out, int out_size, void* d_ws, size_t ws_size,
                              hipStream_t stream) {
  const float* features = (const float*)d_in[0];
  // d_in[1]=W_fk, d_in[2]=b_fk, d_in[5]=W_tk, d_in[6]=b_tk : dead code (softmax over size-1 axis)
  const float* W_fv = (const float*)d_in[3];
  const float* b_fv = (const float*)d_in[4];
  const float* W_ih = (const float*)d_in[7];
  const float* W_hh = (const float*)d_in[8];
  const float* b_ih = (const float*)d_in[9];
  const float* b_hh = (const float*)d_in[10];
  const float* W_lm = (const float*)d_in[11];
  const float* b_lm = (const float*)d_in[12];
  const float* bos  = (const float*)d_in[13];
  float* out = (float*)d_out;
  char* ws = (char*)d_ws;

  __hip_bfloat16* WT     = (__hip_bfloat16*)(ws + OFF_WT);
  __hip_bfloat16* H      = (__hip_bfloat16*)(ws + OFF_H);
  unsigned long long* Hq = (unsigned long long*)(ws + OFF_H);
  float* fsum            = (float*)(ws + OFF_FSUM);
  float* ctx             = (float*)(ws + OFF_CTX);
  float* gbase           = (float*)(ws + OFF_GBASE);

  hipLaunchKernelGGL(k_fsum,  dim3(384),    dim3(256), 0, stream, features, fsum, Hq);
  hipLaunchKernelGGL(k_ctx,   dim3(16, 2),  dim3(256), 0, stream, fsum, W_fv, b_fv, ctx);
  hipLaunchKernelGGL(k_gbase, dim3(16, 2),  dim3(256), 0, stream, ctx, W_ih, b_ih, b_hh, gbase);
  // blocks 0..127: recurrence; 128..255: one-hot + pad zero + W_lm->WT (concurrent, NT)
  hipLaunchKernelGGL(k_rec,   dim3(256),  dim3(256), 163840, stream,
                     gbase, W_hh, bos, Hq, W_lm, WT, out);
  hipLaunchKernelGGL(k_gemm,  dim3(1625), dim3(512), 131072, stream, H, WT, b_lm, out);
}

// Round 14
// 758.172 us; speedup vs baseline: 2.2820x; 1.1719x over previous
//
#include <hip/hip_runtime.h>
#include <hip/hip_bf16.h>
#include <stdint.h>

typedef __attribute__((ext_vector_type(8))) short short8;
typedef __attribute__((ext_vector_type(4))) float f32x4;

#define B_ 32
#define N_ 196
#define D_ 1024
#define V_ 32000
#define NSTEP 99
#define MROWS 3168   // 99*32
#define MPAD  3200
#define SENT  0x7FC07FC07FC07FC0ULL   // 4x bf16 NaN: unreachable as packed h (|h|<1)

// workspace layout (bytes)
#define OFF_WT     0ULL          // bf16 [32000][1024]  = 65,536,000
#define OFF_H      65536000ULL   // bf16 [3200][1024]   =  6,553,600  (u64 view: [99][8192] + pad)
#define OFF_FSUM   72089600ULL   // f32  [32][1024]
#define OFF_CTXP   72220672ULL   // f32  [2][32][1024]  partials
#define OFF_GBASEP 72482816ULL   // f32  [4][32][4096]  partials

#define AS3 __attribute__((address_space(3)))
#define AS1 __attribute__((address_space(1)))
static __device__ __forceinline__ void gload_lds16(const void* g, void* l) {
  __builtin_amdgcn_global_load_lds((const AS1 uint32_t*)g, (AS3 uint32_t*)l, 16, 0, 0);
}

// ---------------- fsum (blocks 0..127) + sentinel-fill H (blocks 128..383) ----------------
__global__ void k_fsum(const float* __restrict__ feat, float* __restrict__ fsum,
                       unsigned long long* __restrict__ Hq) {
  if (blockIdx.x >= 128) {
    int gid = (blockIdx.x - 128) * 256 + threadIdx.x;   // 65536 threads
    for (int w = gid; w < NSTEP * 8192; w += 65536) Hq[w] = SENT;
    return;
  }
  int idx = blockIdx.x * 256 + threadIdx.x;           // 32768
  int b = idx >> 10, e = idx & 1023;
  const float* p = feat + (size_t)b * (N_ * D_) + e;
  float s = 0.f;
  #pragma unroll 4
  for (int n = 0; n < N_; ++n) s += fmaxf(p[(size_t)n * D_], 0.f);
  fsum[idx] = s;
}

// ---------------- ctxp[kc] = fsum[:,e-chunk] @ W_fv[e-chunk,:] (+196*b_fv in kc0) ----------------
// split-K: grid (16, 2, 2) = 64 blocks
__global__ void k_ctx(const float* __restrict__ fsum, const float* __restrict__ W_fv,
                      const float* __restrict__ b_fv, float* __restrict__ ctxp) {
  __shared__ float fs[16][512];                       // 32 KB
  int kc = blockIdx.z;                                // e-chunk 0..1
  int e0 = kc * 512;
  int b0 = blockIdx.y * 16;
  int d = blockIdx.x * 64 + (threadIdx.x & 63);
  int bq = threadIdx.x >> 6;                          // 4 batch-quads
  for (int i = threadIdx.x; i < 8192; i += 256)
    fs[i >> 9][i & 511] = fsum[(b0 + (i >> 9)) * 1024 + e0 + (i & 511)];
  __syncthreads();
  float bias = (kc == 0) ? 196.f * b_fv[d] : 0.f;
  float acc[4] = {bias, bias, bias, bias};
  for (int e4 = 0; e4 < 128; ++e4) {
    float w0 = W_fv[(size_t)(e0 + 4 * e4 + 0) * 1024 + d];
    float w1 = W_fv[(size_t)(e0 + 4 * e4 + 1) * 1024 + d];
    float w2 = W_fv[(size_t)(e0 + 4 * e4 + 2) * 1024 + d];
    float w3 = W_fv[(size_t)(e0 + 4 * e4 + 3) * 1024 + d];
    #pragma unroll
    for (int r = 0; r < 4; ++r) {
      float4 c = *(const float4*)&fs[bq * 4 + r][e4 * 4];
      acc[r] = fmaf(c.x, w0, fmaf(c.y, w1, fmaf(c.z, w2, fmaf(c.w, w3, acc[r]))));
    }
  }
  #pragma unroll
  for (int r = 0; r < 4; ++r)
    ctxp[kc * 32768 + (size_t)(b0 + bq * 4 + r) * 1024 + d] = acc[r];
}

// ---------------- gbasep[kc] = ctx[:,e-chunk] @ W_ih[e-chunk,:] (+biases in kc0) ----------------
// split-K: grid (16, 2, 4) = 128 blocks; ctx = sum of 2 ctx partials (fused here)
__global__ void k_gbase(const float* __restrict__ ctxp, const float* __restrict__ W_ih,
                        const float* __restrict__ b_ih, const float* __restrict__ b_hh,
                        float* __restrict__ gbasep) {
  __shared__ float cs[16][256];                       // 16 KB
  int kc = blockIdx.z;                                // e-chunk 0..3
  int e0 = kc * 256;
  int b0 = blockIdx.y * 16;
  int j = blockIdx.x * 256 + threadIdx.x;
  for (int i = threadIdx.x; i < 4096; i += 256) {
    int r = i >> 8, e = i & 255;
    cs[r][e] = ctxp[(size_t)(b0 + r) * 1024 + e0 + e]
             + ctxp[32768 + (size_t)(b0 + r) * 1024 + e0 + e];
  }
  __syncthreads();
  float bias = (kc == 0) ? (b_ih[j] + b_hh[j]) : 0.f;
  float acc[16];
  #pragma unroll
  for (int r = 0; r < 16; ++r) acc[r] = bias;
  for (int e4 = 0; e4 < 64; ++e4) {
    float w0 = W_ih[(size_t)(e0 + 4 * e4 + 0) * 4096 + j];
    float w1 = W_ih[(size_t)(e0 + 4 * e4 + 1) * 4096 + j];
    float w2 = W_ih[(size_t)(e0 + 4 * e4 + 2) * 4096 + j];
    float w3 = W_ih[(size_t)(e0 + 4 * e4 + 3) * 4096 + j];
    #pragma unroll
    for (int r = 0; r < 16; ++r) {
      float4 c = *(const float4*)&cs[r][e4 * 4];
      acc[r] = fmaf(c.x, w0, fmaf(c.y, w1, fmaf(c.z, w2, fmaf(c.w, w3, acc[r]))));
    }
  }
  #pragma unroll
  for (int r = 0; r < 16; ++r)
    gbasep[kc * 131072 + (size_t)(b0 + r) * 4096 + j] = acc[r];
}

// ---------------- persistent LSTM recurrence (blocks 0..127) + workers (128..255) ----------------
// 2-D decomposition (round-12/13 validated): block (bh,dg) owns 16 batches x 16 dims.
__global__ __launch_bounds__(256, 1) void k_rec(
    const float* __restrict__ gbasep, const float* __restrict__ W_hh,
    const float* __restrict__ bos, unsigned long long* __restrict__ Hq,
    const float* __restrict__ W_lm, __hip_bfloat16* __restrict__ WT,
    float* __restrict__ out) {
  extern __shared__ char lds[];
  const int tid = threadIdx.x;
  const int blk = blockIdx.x;

  if (blk >= 128) {
    // ---------- worker blocks ----------
    __hip_bfloat16* t = (__hip_bfloat16*)lds;          // [64][66]
    int wblk = blk - 128;
    for (int idx = wblk * 256 + tid; idx < B_ * V_; idx += 128 * 256)
      __builtin_nontemporal_store(((idx % V_) == 0) ? 1.0f : 0.0f, &out[idx]);
    // zero TRUE pad rows 3168..3199 (256 u64 per row)
    if (wblk < 64) ((uint32_t*)(Hq + (size_t)MROWS * 256))[wblk * 256 + tid] = 0u;
    int tx = tid & 63, ty = tid >> 6;
    int word = tx & 31, nh = tx >> 5;
    for (int tile = wblk; tile < 8000; tile += 128) {
      int k0 = (tile & 15) * 64;
      int n0 = (tile >> 4) * 64;
      __syncthreads();
      #pragma unroll
      for (int i = 0; i < 16; ++i) {
        int r = i * 4 + ty;
        t[r * 66 + tx] = __float2bfloat16(
            __builtin_nontemporal_load(&W_lm[(size_t)(k0 + r) * V_ + n0 + tx]));
      }
      __syncthreads();
      #pragma unroll
      for (int i = 0; i < 8; ++i) {
        int n = i * 8 + ty * 2 + nh;
        uint32_t lo = *(const uint16_t*)&t[2 * word * 66 + n];
        uint32_t hi = *(const uint16_t*)&t[(2 * word + 1) * 66 + n];
        __builtin_nontemporal_store(lo | (hi << 16),
            (uint32_t*)&WT[(size_t)(n0 + n) * 1024 + k0] + word);
      }
    }
    return;
  }

  // ---------- recurrence blocks ----------
  __hip_bfloat16* hbuf = (__hip_bfloat16*)lds;             // [16][1024] swizzled (32 KB)
  __hip_bfloat16* wbuf = (__hip_bfloat16*)(lds + 32768);   // [64][1024] (init only, 128 KB)
  float* gex = (float*)(lds + 32768);                      // [16][68] f32, aliases wbuf

  const int bh = blk >> 6;     // batch half 0..1
  const int dg = blk & 63;     // dim group 0..63 (dims dg*16..+16)

  for (int idx = tid; idx < 64 * 1024; idx += 256) {
    int c = idx & 63;
    int k = idx >> 6;
    float w = W_hh[(size_t)k * 4096 + (c >> 4) * 1024 + dg * 16 + (c & 15)];
    wbuf[c * 1024 + ((((k >> 3) ^ (c & 7)) << 3) | (k & 7))] = __float2bfloat16(w);
  }
  for (int idx = tid; idx < 16 * 1024; idx += 256) {
    int row = idx >> 10;
    int k = idx & 1023;
    hbuf[row * 1024 + ((((k >> 3) ^ (row & 7)) << 3) | (k & 7))] = __float2bfloat16(bos[k]);
  }

  const int btl = tid >> 4;    // local batch 0..15
  const int dl = tid & 15;     // local dim 0..15
  float gb0 = 0.f, gb1 = 0.f, gb2 = 0.f, gb3 = 0.f;
  #pragma unroll
  for (int kc = 0; kc < 4; ++kc) {
    size_t base = (size_t)kc * 131072 + (size_t)(bh * 16 + btl) * 4096 + dg * 16 + dl;
    gb0 += gbasep[base + 0 * 1024];
    gb1 += gbasep[base + 1 * 1024];
    gb2 += gbasep[base + 2 * 1024];
    gb3 += gbasep[base + 3 * 1024];
  }
  float cst = 0.f;

  const int lane = tid & 63;
  const int wid = tid >> 6;          // 0..3 : wave owns local cols wid*16..+16
  const int arow = lane & 15;        // batch row (single 16-row tile)
  const int bcol = wid * 16 + (lane & 15);
  const int kg = lane >> 4;
  const int axor = arow & 7;

  __syncthreads();

  short8 breg[32];
  #pragma unroll
  for (int kt = 0; kt < 32; ++kt) {
    int ca = kt * 4 + kg;
    breg[kt] = *(const short8*)&wbuf[bcol * 1024 + ((ca ^ (bcol & 7)) << 3)];
  }

  const int pubw = (bh * 16 + btl) * 256 + dg * 4 + (dl >> 2);

  for (int t = 0; t < NSTEP; ++t) {
    f32x4 acc0 = {0.f, 0.f, 0.f, 0.f};
    f32x4 acc1 = {0.f, 0.f, 0.f, 0.f};
    #pragma unroll
    for (int kt = 0; kt < 32; kt += 2) {
      int ca = kt * 4 + kg;
      short8 a0 = *(const short8*)&hbuf[arow * 1024 + ((ca ^ axor) << 3)];
      acc0 = __builtin_amdgcn_mfma_f32_16x16x32_bf16(a0, breg[kt], acc0, 0, 0, 0);
      short8 a1 = *(const short8*)&hbuf[arow * 1024 + (((ca + 4) ^ axor) << 3)];
      acc1 = __builtin_amdgcn_mfma_f32_16x16x32_bf16(a1, breg[kt + 1], acc1, 0, 0, 0);
    }
    acc0 = acc0 + acc1;
    __syncthreads();
    {
      int bq = (lane >> 4) << 2;
      #pragma unroll
      for (int q = 0; q < 4; ++q) gex[(bq + q) * 68 + bcol] = acc0[q];
    }
    __syncthreads();   // S1

    float gi = gex[btl * 68 + 0  + dl] + gb0;
    float gf = gex[btl * 68 + 16 + dl] + gb1;
    float gg = gex[btl * 68 + 32 + dl] + gb2;
    float go = gex[btl * 68 + 48 + dl] + gb3;
    float si = 1.f / (1.f + __expf(-gi));
    float sf = 1.f / (1.f + __expf(-gf));
    float so = 1.f / (1.f + __expf(-go));
    cst = sf * cst + si * tanhf(gg);
    float h = so * tanhf(cst);

    float h1 = __shfl_down(h, 1);
    float h2 = __shfl_down(h, 2);
    float h3 = __shfl_down(h, 3);
    if ((dl & 3) == 0) {
      __hip_bfloat16 q0 = __float2bfloat16(h), q1 = __float2bfloat16(h1);
      __hip_bfloat16 q2 = __float2bfloat16(h2), q3 = __float2bfloat16(h3);
      unsigned long long v = (unsigned long long)*(uint16_t*)&q0
                           | ((unsigned long long)*(uint16_t*)&q1 << 16)
                           | ((unsigned long long)*(uint16_t*)&q2 << 32)
                           | ((unsigned long long)*(uint16_t*)&q3 << 48);
      __hip_atomic_store(&Hq[(size_t)t * 8192 + pubw], v,
                         __ATOMIC_RELAXED, __HIP_MEMORY_SCOPE_AGENT);
    }

    if (t == NSTEP - 1) break;

    {
      const unsigned long long* src = Hq + (size_t)t * 8192 + (size_t)bh * 16 * 256;
      for (;;) {
        unsigned long long v[16];
        #pragma unroll
        for (int j = 0; j < 16; ++j)
          v[j] = __hip_atomic_load(&src[j * 256 + tid],
                                   __ATOMIC_RELAXED, __HIP_MEMORY_SCOPE_AGENT);
        int nready = 0;
        #pragma unroll
        for (int j = 0; j < 16; ++j) {
          if (v[j] != SENT) {
            int off = (((tid >> 1) ^ (j & 7)) << 3) + ((tid & 1) << 2);
            *(uint2*)&hbuf[j * 1024 + off] = *(uint2*)&v[j];
            ++nready;
          }
        }
        if (nready == 16) break;
        __builtin_amdgcn_s_sleep(1);
      }
    }
    __syncthreads();   // S2
  }
}

// ---------------- logits GEMM: 256x256, ONE-barrier dbuf loop (T3-minimum), NT epilogue ----------------
// STAGE(next) -> COMPUTE(cur) -> vmcnt(0) -> barrier: next-tile loads get a full compute
// phase of latency cover; one barrier per K-tile (16 vs 32). GM=13 raster + NT stores.
__global__ __launch_bounds__(512, 1) void k_gemm(
    const __hip_bfloat16* __restrict__ H,    // [3200][1024] (rows 3168..3199 zero)
    const __hip_bfloat16* __restrict__ WT,   // [32000][1024]
    const float* __restrict__ b_lm,
    float* __restrict__ out) {
  extern __shared__ char glds[];
  __hip_bfloat16* As = (__hip_bfloat16*)glds;            // [2][256*64] = 64 KB
  __hip_bfloat16* Bs = (__hip_bfloat16*)(glds + 65536);  // [2][256*64] = 64 KB

  // XCD-bijective remap: nwg = 1625 = 8*203 + 1
  int bid = blockIdx.x;
  int xcd = bid & 7;
  int idx = bid >> 3;
  int wg = (xcd < 1 ? xcd * 204 : 204 + (xcd - 1) * 203) + idx;
  // GM=13 raster: all 13 m-tiles consecutive per B panel (nt), mt fastest
  int nt = wg / 13;            // 0..124
  int mt = wg - nt * 13;       // 0..12
  const int mbase = mt * 256;
  const int nbase = nt * 256;

  const int tid = threadIdx.x;
  const int lane = tid & 63;
  const int wid = tid >> 6;      // 0..7
  const int wm = wid >> 2;       // 0..1  (M 128-half)
  const int wn = wid & 3;        // 0..3  (N 64-quarter)

  f32x4 acc[8][4];
  #pragma unroll
  for (int m = 0; m < 8; ++m)
    #pragma unroll
    for (int n = 0; n < 4; ++n) acc[m][n] = (f32x4){0.f, 0.f, 0.f, 0.f};

  const int kg = lane >> 4;

  int srowA[4], srowB[4], soff[4];
  #pragma unroll
  for (int j = 0; j < 4; ++j) {
    int c = j * 512 + tid;
    int row = c >> 3;
    srowB[j] = nbase + row;
    srowA[j] = min(mbase + row, MPAD - 1);   // clamp pad rows (zeros)
    soff[j] = ((c & 7) ^ (row & 7)) * 8;
  }
  const int ldsbase = (tid & 448) * 8;

  auto STAGE = [&](int nb, int kt) {
    #pragma unroll
    for (int j = 0; j < 4; ++j)
      gload_lds16(H + (size_t)srowA[j] * 1024 + kt * 64 + soff[j],
                  As + nb * 16384 + j * 4096 + ldsbase);
    #pragma unroll
    for (int j = 0; j < 4; ++j)
      gload_lds16(WT + (size_t)srowB[j] * 1024 + kt * 64 + soff[j],
                  Bs + nb * 16384 + j * 4096 + ldsbase);
  };
  auto COMPUTE = [&](int nb) {
    __builtin_amdgcn_s_setprio(1);
    #pragma unroll
    for (int kk = 0; kk < 2; ++kk) {
      const int slot = kk * 4 + kg;
      short8 a[8], b[4];
      #pragma unroll
      for (int m = 0; m < 8; ++m) {
        int r = wm * 128 + m * 16 + (lane & 15);
        a[m] = *(const short8*)&As[nb * 16384 + r * 64 + ((slot ^ (r & 7)) << 3)];
      }
      #pragma unroll
      for (int n = 0; n < 4; ++n) {
        int r = wn * 64 + n * 16 + (lane & 15);
        b[n] = *(const short8*)&Bs[nb * 16384 + r * 64 + ((slot ^ (r & 7)) << 3)];
      }
      #pragma unroll
      for (int m = 0; m < 8; ++m)
        #pragma unroll
        for (int n = 0; n < 4; ++n)
          acc[m][n] = __builtin_amdgcn_mfma_f32_16x16x32_bf16(a[m], b[n], acc[m][n], 0, 0, 0);
    }
    __builtin_amdgcn_s_setprio(0);
  };

  // prologue: tile 0 resident
  STAGE(0, 0);
  asm volatile("s_waitcnt vmcnt(0)" ::: "memory");
  __builtin_amdgcn_s_barrier();
  for (int kt = 0; kt < 16; ++kt) {
    if (kt < 15) STAGE((kt + 1) & 1, kt + 1);     // issue next-tile loads first
    COMPUTE(kt & 1);                              // ds_read + MFMA on current
    asm volatile("s_waitcnt vmcnt(0)" ::: "memory");  // next tile landed (full cover)
    __builtin_amdgcn_s_barrier();                 // all waves done reading cur
  }

  if (mt != 12) {
    #pragma unroll
    for (int n = 0; n < 4; ++n) {
      int gcol = nbase + wn * 64 + n * 16 + (lane & 15);
      float bl = b_lm[gcol];
      #pragma unroll
      for (int m = 0; m < 8; ++m) {
        int rbase = mbase + wm * 128 + m * 16 + ((lane >> 4) << 2);
        #pragma unroll
        for (int q = 0; q < 4; ++q)
          __builtin_nontemporal_store(acc[m][n][q] + bl,
              &out[(size_t)(rbase + q + 32) * V_ + gcol]);
      }
    }
  } else {
    #pragma unroll
    for (int n = 0; n < 4; ++n) {
      int gcol = nbase + wn * 64 + n * 16 + (lane & 15);
      float bl = b_lm[gcol];
      #pragma unroll
      for (int m = 0; m < 8; ++m) {
        int rbase = mbase + wm * 128 + m * 16 + ((lane >> 4) << 2);
        #pragma unroll
        for (int q = 0; q < 4; ++q) {
          int r = rbase + q;
          if (r < MROWS)
            __builtin_nontemporal_store(acc[m][n][q] + bl,
                &out[(size_t)(r + 32) * V_ + gcol]);
        }
      }
    }
  }
}

extern "C" void kernel_launch(void* const* d_in, const int* in_sizes, int n_in,
                              void* d_out, int out_size, void* d_ws, size_t ws_size,
                              hipStream_t stream) {
  const float* features = (const float*)d_in[0];
  // d_in[1]=W_fk, d_in[2]=b_fk, d_in[5]=W_tk, d_in[6]=b_tk : dead code (softmax over size-1 axis)
  const float* W_fv = (const float*)d_in[3];
  const float* b_fv = (const float*)d_in[4];
  const float* W_ih = (const float*)d_in[7];
  const float* W_hh = (const float*)d_in[8];
  const float* b_ih = (const float*)d_in[9];
  const float* b_hh = (const float*)d_in[10];
  const float* W_lm = (const float*)d_in[11];
  const float* b_lm = (const float*)d_in[12];
  const float* bos  = (const float*)d_in[13];
  float* out = (float*)d_out;
  char* ws = (char*)d_ws;

  __hip_bfloat16* WT     = (__hip_bfloat16*)(ws + OFF_WT);
  __hip_bfloat16* H      = (__hip_bfloat16*)(ws + OFF_H);
  unsigned long long* Hq = (unsigned long long*)(ws + OFF_H);
  float* fsum            = (float*)(ws + OFF_FSUM);
  float* ctxp            = (float*)(ws + OFF_CTXP);
  float* gbasep          = (float*)(ws + OFF_GBASEP);

  hipLaunchKernelGGL(k_fsum,  dim3(384),       dim3(256), 0, stream, features, fsum, Hq);
  hipLaunchKernelGGL(k_ctx,   dim3(16, 2, 2),  dim3(256), 0, stream, fsum, W_fv, b_fv, ctxp);
  hipLaunchKernelGGL(k_gbase, dim3(16, 2, 4),  dim3(256), 0, stream, ctxp, W_ih, b_ih, b_hh, gbasep);
  // blocks 0..127: recurrence; 128..255: one-hot + pad zero + W_lm->WT (concurrent, NT)
  hipLaunchKernelGGL(k_rec,   dim3(256),  dim3(256), 163840, stream,
                     gbasep, W_hh, bos, Hq, W_lm, WT, out);
  hipLaunchKernelGGL(k_gemm,  dim3(1625), dim3(512), 131072, stream, H, WT, b_lm, out);
}